// Round 18
// baseline (389.124 us; speedup 1.0000x reference)
//
#include <hip/hip_runtime.h>
#include <hip/hip_bf16.h>

typedef __bf16 bf16x8 __attribute__((ext_vector_type(8)));
typedef float  f32x4  __attribute__((ext_vector_type(4)));

#define B_SZ 4096
#define I_SZ 512
#define O_SZ 64
#define E_SZ 128
#define BM   256
#define G_EXP 8      // experts per workgroup (K-split group size)
#define EG_N  16     // expert groups
#define MT_N  16     // m tiles (4096/256)

// ---------------- fused prep: x f32->bf16  +  gT[e][b] ----------------
__global__ void prep_xg(const float* __restrict__ x, __bf16* __restrict__ xb,
                        const float* __restrict__ ds, const float* __restrict__ ts,
                        float* __restrict__ gT) {
  int i = blockIdx.x * 256 + threadIdx.x;          // 524288 = B*I/4 = E*B
  float4 v = ((const float4*)x)[i];
  union { __bf16 h[4]; ushort4 u4; } pk;
  pk.h[0] = (__bf16)v.x; pk.h[1] = (__bf16)v.y;
  pk.h[2] = (__bf16)v.z; pk.h[3] = (__bf16)v.w;
  ((ushort4*)xb)[i] = pk.u4;
  int e = i >> 12, b = i & 4095;
  gT[i] = ds[b * 32 + (e >> 2)] * ts[b * 4 + (e & 3)];
}

// ---------------- prep: W [e][i][o] f32 -> wt [e][o][i] bf16 ----------------
__global__ void prep_w(const float* __restrict__ W, __bf16* __restrict__ wt) {
  __shared__ __bf16 tile[64][66];
  int e  = blockIdx.x >> 3;
  int it = blockIdx.x & 7;
  const float* src = W + (size_t)e * I_SZ * O_SZ + (size_t)it * 64 * O_SZ;
  #pragma unroll
  for (int s = 0; s < 16; ++s) {
    int idx = s * 256 + threadIdx.x;
    int r = idx >> 6, o = idx & 63;
    tile[o][r] = (__bf16)src[idx];
  }
  __syncthreads();
  __bf16* dst = wt + (size_t)e * O_SZ * I_SZ + it * 64;
  #pragma unroll
  for (int s = 0; s < 4; ++s) {
    int idx = s * 256 + threadIdx.x;
    int o = idx >> 4, c = (idx & 15) << 2;
    union { __bf16 h[4]; ushort4 u4; } q;
    q.h[0] = tile[o][c + 0]; q.h[1] = tile[o][c + 1];
    q.h[2] = tile[o][c + 2]; q.h[3] = tile[o][c + 3];
    *(ushort4*)&dst[(size_t)o * I_SZ + c] = q.u4;
  }
}

// ---------------- main: Mf=4 via K-quarter windows; LDS B-traffic halved -------
// 8 waves = 4 row-groups(64 r) x 2 O-halves(32 o); BM=256. K-quarter outer loop:
// af window = af[4][4] (64 VGPR) -> Mf=4 WITHOUT the 256-reg af wall that killed
// R11/R12/R14. Gating is linear: per-quarter partials drain into logits with the
// same g. LDS: 8 slots x 16KB (one expert-quarter each) = 128KB single-buffered;
// slot[e] dies after expert e, restaged for q+1 at boundary e+1 (7-boundary
// slack, 14-deep constant DMA pipeline). Exact counted vmcnt: (q,0) = vmcnt(2)
// after af(16)+pair issue (af older than pair -> af landed, FIFO); (q,7) =
// vmcnt(12) (12 pairs issued after slot7<-q's pair); elsewhere none needed.
// Full q x e unroll -> all immediates/indices compile-time. Zero-conflict
// chunked reads (128B rows). Bias folded at q==0 acc-init. bf16 partials.
__global__ __launch_bounds__(512, 2)
void mtc_gemm(const __bf16* __restrict__ xb, const __bf16* __restrict__ wt,
              const float* __restrict__ gT, const float* __restrict__ bias,
              __bf16* __restrict__ partials) {
  __shared__ __align__(16) __bf16 wsh[8][2][64 * 64]; // slot[e][chunk]: 128KB
  __shared__ float gsh[G_EXP][BM];                    // 8KB gates
  __shared__ float bsh[G_EXP][O_SZ];                  // 2KB bias

  const int tid  = threadIdx.x;
  const int wave = tid >> 6;
  const int lane = tid & 63;
  const int rg   = wave >> 1;                         // row-group (64 rows)
  const int oh   = wave & 1;                          // O-half (32 cols)

  // XCD swizzle: 256 blocks -> 32 consecutive per XCD
  int bid = (int)blockIdx.x;
  bid = (bid & 7) * 32 + (bid >> 3);
  const int mtile = bid & 15;
  const int eg    = bid >> 4;
  const int row0  = mtile * BM;
  const int e0    = eg * G_EXP;

  // stage pair: expert `slot`'s K-quarter q -> wsh[slot] (2 DMAs/thread, 16KB).
  // dest linear [o=tid>>3][physslot p=tid&7]; source slot sl = p^(o&7).
  auto stagep = [&](int slot, int q) {
    const __bf16* wsrc = wt + (size_t)(e0 + slot) * O_SZ * I_SZ + q * 128;
    int o = tid >> 3, p = tid & 7;
    int sl = p ^ (o & 7);
    #pragma unroll
    for (int d = 0; d < 2; ++d)
      __builtin_amdgcn_global_load_lds(
          (const __attribute__((address_space(1))) void*)(wsrc + (size_t)o * I_SZ + d * 64 + sl * 8),
          (__attribute__((address_space(3))) void*)(&wsh[slot][d][tid * 8]),
          16, 0, 0);
  };

  // prologue: stage all 8 slots for q=0; fill gates + bias
  #pragma unroll
  for (int e = 0; e < 8; ++e) stagep(e, 0);

  for (int idx = tid; idx < G_EXP * BM; idx += 512)
    gsh[idx >> 8][idx & 255] =
        gT[(size_t)(e0 + (idx >> 8)) * B_SZ + row0 + (idx & 255)];

  bsh[tid >> 6][tid & 63] = bias[(size_t)e0 * O_SZ + tid];   // 512 = G_EXP*O_SZ

  __syncthreads();                     // drains q=0 slots + gates + bias

  bf16x8 af[4][4];                     // 64 VGPR K-quarter A-window
  f32x4 logits[4][2] = {};             // [mf][nf] gated accumulation

  #pragma unroll
  for (int q = 0; q < 4; ++q) {
    #pragma unroll
    for (int e = 0; e < 8; ++e) {
      // ---- boundary (q,e) ----
      if (e == 0) {
        if (q > 0) __builtin_amdgcn_s_barrier();     // expert7@q-1 readers done
        // af window for this quarter (issued BEFORE the pair: af older in FIFO)
        const __bf16* xr = xb + (size_t)(row0 + rg * 64 + (lane & 15)) * I_SZ
                              + q * 128 + (lane >> 4) * 8;
        #pragma unroll
        for (int mf = 0; mf < 4; ++mf)
          #pragma unroll
          for (int j = 0; j < 4; ++j)
            af[mf][j] = *(const bf16x8*)(xr + mf * 16 * I_SZ + j * 32);
        if (q > 0) stagep(7, q);                     // slot7<-q (died at q-1,e7)
        if (q == 0) { asm volatile("s_waitcnt vmcnt(0)" ::: "memory"); }
        else        { asm volatile("s_waitcnt vmcnt(2)" ::: "memory"); }
        __builtin_amdgcn_s_barrier();                // all waves' DMAs visible
      } else if (e == 7) {
        if (q < 3) { asm volatile("s_waitcnt vmcnt(12)" ::: "memory"); }
        else       { asm volatile("s_waitcnt vmcnt(0)"  ::: "memory"); }
        __builtin_amdgcn_s_barrier();                // slot7@q landed, readers done
        if (q < 3) stagep(6, q + 1);
      } else {
        __builtin_amdgcn_s_barrier();                // slot[e-1]@q readers done
        if (q < 3) stagep(e - 1, q + 1);
      }

      // ---- compute cell (q,e): 8 ds_read_b128 + 32 MFMA ----
      f32x4 acc[4];
      float bv0 = (q == 0) ? bsh[e][oh * 32 + 0 * 16 + (lane & 15)] : 0.f;
      float bv1 = (q == 0) ? bsh[e][oh * 32 + 1 * 16 + (lane & 15)] : 0.f;
      f32x4 accB[4];
      #pragma unroll
      for (int mf = 0; mf < 4; ++mf) {
        acc[mf]  = (f32x4){bv0, bv0, bv0, bv0};
        accB[mf] = (f32x4){bv1, bv1, bv1, bv1};
      }
      __builtin_amdgcn_s_setprio(1);
      #pragma unroll
      for (int j = 0; j < 4; ++j) {                  // K32 steps; chunk = j>>1
        const __bf16* wb = &wsh[e][j >> 1][0];
        int qsl = (j & 1) * 4 + (lane >> 4);
        int o0  = oh * 32 + (lane & 15);
        int o1  = o0 + 16;
        bf16x8 b0 = *(const bf16x8*)(wb + o0 * 64 + (qsl ^ (o0 & 7)) * 8);
        bf16x8 b1 = *(const bf16x8*)(wb + o1 * 64 + (qsl ^ (o1 & 7)) * 8);
        #pragma unroll
        for (int mf = 0; mf < 4; ++mf) {
          acc[mf]  = __builtin_amdgcn_mfma_f32_16x16x32_bf16(af[mf][j], b0, acc[mf],  0, 0, 0);
          accB[mf] = __builtin_amdgcn_mfma_f32_16x16x32_bf16(af[mf][j], b1, accB[mf], 0, 0, 0);
        }
      }
      __builtin_amdgcn_s_setprio(0);

      // gated drain (C/D: col=lane&15 within 16-block, row=(lane>>4)*4+rgi)
      #pragma unroll
      for (int mf = 0; mf < 4; ++mf) {
        f32x4 gq = *(const f32x4*)&gsh[e][rg * 64 + mf * 16 + (lane >> 4) * 4];
        #pragma unroll
        for (int rgi = 0; rgi < 4; ++rgi) {
          logits[mf][0][rgi] += gq[rgi] * acc[mf][rgi];
          logits[mf][1][rgi] += gq[rgi] * accB[mf][rgi];
        }
      }
    }
  }

  // epilogue: bf16 partial slab per expert-group (waves disjoint: rg x oh)
  __bf16* pout = partials + (size_t)eg * B_SZ * O_SZ + (size_t)row0 * O_SZ;
  #pragma unroll
  for (int mf = 0; mf < 4; ++mf)
    #pragma unroll
    for (int nf = 0; nf < 2; ++nf)
      #pragma unroll
      for (int rgi = 0; rgi < 4; ++rgi) {
        int r = rg * 64 + mf * 16 + ((lane >> 4) << 2) + rgi;
        int o = oh * 32 + nf * 16 + (lane & 15);
        pout[(size_t)r * O_SZ + o] = (__bf16)logits[mf][nf][rgi];
      }
}

// ---------------- reduce: sum 16 bf16 partial slabs + log_softmax --------------
__global__ __launch_bounds__(256)
void mtc_reduce(const __bf16* __restrict__ partials, float* __restrict__ out) {
  int wave = threadIdx.x >> 6, lane = threadIdx.x & 63;
  int r = blockIdx.x * 4 + wave;                    // one 64-lane wave per row
  float s = 0.f;
  #pragma unroll
  for (int k = 0; k < EG_N; ++k)
    s += (float)partials[(size_t)k * B_SZ * O_SZ + (size_t)r * O_SZ + lane];
  float m = s;
  #pragma unroll
  for (int off = 32; off; off >>= 1) m = fmaxf(m, __shfl_xor(m, off));
  float ex = expf(s - m), sum = ex;
  #pragma unroll
  for (int off = 32; off; off >>= 1) sum += __shfl_xor(sum, off);
  out[(size_t)r * O_SZ + lane] = s - m - logf(sum);
}

extern "C" void kernel_launch(void* const* d_in, const int* in_sizes, int n_in,
                              void* d_out, int out_size, void* d_ws, size_t ws_size,
                              hipStream_t stream) {
  const float* x    = (const float*)d_in[0];
  const float* ds   = (const float*)d_in[1];
  const float* ts   = (const float*)d_in[2];
  const float* W    = (const float*)d_in[3];
  const float* bias = (const float*)d_in[4];
  float* out = (float*)d_out;

  char* w = (char*)d_ws;
  __bf16* xb      = (__bf16*)(w);                   // 4 MB
  __bf16* wt      = (__bf16*)(w + (4ull  << 20));   // 8 MB
  float*  gT      = (float*) (w + (12ull << 20));   // 2 MB
  __bf16* parts   = (__bf16*)(w + (14ull << 20));   // 8 MB (16 slabs x 512KB)

  prep_xg   <<<2048, 256, 0, stream>>>(x, xb, ds, ts, gT);
  prep_w    <<<1024, 256, 0, stream>>>(W, wt);
  mtc_gemm  <<< 256, 512, 0, stream>>>(xb, wt, gT, bias, parts);
  mtc_reduce<<<1024, 256, 0, stream>>>(parts, out);
}

// Round 19
// 56.806 us; speedup vs baseline: 6.8501x; 6.8501x over previous
//
#include <hip/hip_runtime.h>
#include <hip/hip_bf16.h>

typedef __bf16 bf16x8 __attribute__((ext_vector_type(8)));
typedef float  f32x4  __attribute__((ext_vector_type(4)));

#define B_SZ 4096
#define I_SZ 512
#define O_SZ 64
#define E_SZ 128
#define BM   256
#define G_EXP 8      // experts per workgroup (K-split group size)
#define EG_N  16     // expert groups
#define MT_N  16     // m tiles (4096/256)

// ---------------- fused prep: x f32->bf16  +  gT[e][b] ----------------
__global__ void prep_xg(const float* __restrict__ x, __bf16* __restrict__ xb,
                        const float* __restrict__ ds, const float* __restrict__ ts,
                        float* __restrict__ gT) {
  int i = blockIdx.x * 256 + threadIdx.x;          // 524288 = B*I/4 = E*B
  float4 v = ((const float4*)x)[i];
  union { __bf16 h[4]; ushort4 u4; } pk;
  pk.h[0] = (__bf16)v.x; pk.h[1] = (__bf16)v.y;
  pk.h[2] = (__bf16)v.z; pk.h[3] = (__bf16)v.w;
  ((ushort4*)xb)[i] = pk.u4;
  int e = i >> 12, b = i & 4095;
  gT[i] = ds[b * 32 + (e >> 2)] * ts[b * 4 + (e & 3)];
}

// ---------------- prep: W [e][i][o] f32 -> wt [e][o][i] bf16 ----------------
__global__ void prep_w(const float* __restrict__ W, __bf16* __restrict__ wt) {
  __shared__ __bf16 tile[64][66];
  int e  = blockIdx.x >> 3;
  int it = blockIdx.x & 7;
  const float* src = W + (size_t)e * I_SZ * O_SZ + (size_t)it * 64 * O_SZ;
  #pragma unroll
  for (int s = 0; s < 16; ++s) {
    int idx = s * 256 + threadIdx.x;
    int r = idx >> 6, o = idx & 63;
    tile[o][r] = (__bf16)src[idx];
  }
  __syncthreads();
  __bf16* dst = wt + (size_t)e * O_SZ * I_SZ + it * 64;
  #pragma unroll
  for (int s = 0; s < 4; ++s) {
    int idx = s * 256 + threadIdx.x;
    int o = idx >> 4, c = (idx & 15) << 2;
    union { __bf16 h[4]; ushort4 u4; } q;
    q.h[0] = tile[o][c + 0]; q.h[1] = tile[o][c + 1];
    q.h[2] = tile[o][c + 2]; q.h[3] = tile[o][c + 3];
    *(ushort4*)&dst[(size_t)o * I_SZ + c] = q.u4;
  }
}

// ---------------- main: R9 verbatim (verified best) + bf16 partials ----------
// 8 waves x 32 rows (Mf=2 of 16) = BM 256; mfma_f32_16x16x32_bf16, Nf=4 covers
// O=64. Chunked [buf][kc][o*64+slot*8] LDS (measured ZERO bank conflicts),
// 2 barriers + counted vmcnt(8) per expert, bias in LDS, setprio around MFMA.
// This structure measured 48.4us with clean counters; 8 structural variants
// (sub-phasing x2, desync, K-split x2, Mf=4 x4) all regressed or spilled.
// Only delta vs R9: partials stored as bf16 (absmax unchanged 0.0625).
__global__ __launch_bounds__(512, 2)
void mtc_gemm(const __bf16* __restrict__ xb, const __bf16* __restrict__ wt,
              const float* __restrict__ gT, const float* __restrict__ bias,
              __bf16* __restrict__ partials) {
  __shared__ __align__(16) __bf16 wsh[2][8][64 * 64];  // [buf][kc][o*64+slot*8] 8KB chunks
  __shared__ float gsh[G_EXP][BM];                     // 8KB gates
  __shared__ float bsh[G_EXP][O_SZ];                   // 2KB bias

  const int tid  = threadIdx.x;
  const int wave = tid >> 6;
  const int lane = tid & 63;

  // XCD swizzle: 256 blocks -> 32 consecutive per XCD
  int bid = (int)blockIdx.x;
  bid = (bid & 7) * 32 + (bid >> 3);
  const int mtile = bid & 15;
  const int eg    = bid >> 4;
  const int row0  = mtile * BM;
  const int e0    = eg * G_EXP;

  // stage whole expert e into wsh[sbuf]: 8 DMAs/thread (512 thr x 16B x 8 = 64KB).
  // dest linear => [o=tid>>3][slot p=tid&7]; source slot sl = p^(o&7) (involution).
  auto stage = [&](int sbuf, int e) {
    const __bf16* wsrc = wt + (size_t)(e0 + e) * O_SZ * I_SZ;
    int o = tid >> 3, p = tid & 7;
    int sl = p ^ (o & 7);
    #pragma unroll
    for (int kc = 0; kc < 8; ++kc) {
      __builtin_amdgcn_global_load_lds(
          (const __attribute__((address_space(1))) void*)(wsrc + (size_t)o * I_SZ + kc * 64 + sl * 8),
          (__attribute__((address_space(3))) void*)(&wsh[sbuf][kc][wave * 512]),
          16, 0, 0);
    }
  };

  // prologue: stage expert 0, overlap with gsh + bias + af loads
  stage(0, 0);

  for (int idx = tid; idx < G_EXP * BM; idx += 512)
    gsh[idx >> 8][idx & 255] =
        gT[(size_t)(e0 + (idx >> 8)) * B_SZ + row0 + (idx & 255)];

  bsh[tid >> 6][tid & 63] = bias[(size_t)e0 * O_SZ + tid];   // 512 = G_EXP*O_SZ

  // x A-fragments: af[mf][j] = x[row0+wave*32+mf*16+(lane&15)][j*32+(lane>>4)*8 ..+8]
  bf16x8 af[2][16];
  {
    const __bf16* xr = xb + (size_t)(row0 + wave * 32 + (lane & 15)) * I_SZ
                          + (lane >> 4) * 8;
    #pragma unroll
    for (int mf = 0; mf < 2; ++mf)
      #pragma unroll
      for (int j = 0; j < 16; ++j)
        af[mf][j] = *(const bf16x8*)(xr + mf * 16 * I_SZ + j * 32);
  }

  __syncthreads();                     // drains DMA(e0) + af + bias + gsh (vmcnt->0)

  f32x4 logits[2][4] = {};
  int buf = 0;
  for (int e = 0; e < G_EXP; ++e) {
    if (e < G_EXP - 1) {
      stage(buf ^ 1, e + 1);                       // 8 DMAs into other buffer
      asm volatile("s_waitcnt vmcnt(8)" ::: "memory");   // stage(e) landed
    } else {
      asm volatile("s_waitcnt vmcnt(0)" ::: "memory");
    }
    __builtin_amdgcn_s_barrier();                  // buf ready for all waves

    // bias from LDS: 4 regs live, lgkmcnt (doesn't disturb vmcnt counting)
    float bv[4];
    #pragma unroll
    for (int nf = 0; nf < 4; ++nf)
      bv[nf] = bsh[e][nf * 16 + (lane & 15)];
    f32x4 acc[2][4];
    #pragma unroll
    for (int mf = 0; mf < 2; ++mf)
      #pragma unroll
      for (int nf = 0; nf < 4; ++nf)
        acc[mf][nf] = (f32x4){bv[nf], bv[nf], bv[nf], bv[nf]};

    __builtin_amdgcn_s_setprio(1);
    #pragma unroll
    for (int j = 0; j < 16; ++j) {                 // K-steps of 32; chunk = j>>1
      const __bf16* wb = &wsh[buf][j >> 1][0];
      bf16x8 bfr[4];
      #pragma unroll
      for (int nf = 0; nf < 4; ++nf) {
        int o  = nf * 16 + (lane & 15);
        int q  = (j & 1) * 4 + (lane >> 4);
        int ph = q ^ (o & 7);
        bfr[nf] = *(const bf16x8*)(wb + o * 64 + ph * 8);
      }
      #pragma unroll
      for (int nf = 0; nf < 4; ++nf)
        #pragma unroll
        for (int mf = 0; mf < 2; ++mf)
          acc[mf][nf] = __builtin_amdgcn_mfma_f32_16x16x32_bf16(
              af[mf][j], bfr[nf], acc[mf][nf], 0, 0, 0);
    }
    __builtin_amdgcn_s_setprio(0);

    // drain: logits += g[row,e] * (xW+b).  C/D: col=lane&15, row=(lane>>4)*4+rg
    f32x4 gq[2];
    #pragma unroll
    for (int mf = 0; mf < 2; ++mf)
      gq[mf] = *(const f32x4*)&gsh[e][wave * 32 + mf * 16 + (lane >> 4) * 4];
    #pragma unroll
    for (int mf = 0; mf < 2; ++mf)
      #pragma unroll
      for (int nf = 0; nf < 4; ++nf)
        #pragma unroll
        for (int rg = 0; rg < 4; ++rg)
          logits[mf][nf][rg] += gq[mf][rg] * acc[mf][nf][rg];

    __builtin_amdgcn_s_barrier();                  // all waves done reading buf
    buf ^= 1;
  }

  __bf16* pout = partials + (size_t)eg * B_SZ * O_SZ + (size_t)row0 * O_SZ;
  #pragma unroll
  for (int mf = 0; mf < 2; ++mf)
    #pragma unroll
    for (int nf = 0; nf < 4; ++nf)
      #pragma unroll
      for (int rg = 0; rg < 4; ++rg) {
        int r = wave * 32 + mf * 16 + ((lane >> 4) << 2) + rg;
        int o = nf * 16 + (lane & 15);
        pout[(size_t)r * O_SZ + o] = (__bf16)logits[mf][nf][rg];
      }
}

// ---------------- reduce: sum 16 bf16 partial slabs + log_softmax --------------
__global__ __launch_bounds__(256)
void mtc_reduce(const __bf16* __restrict__ partials, float* __restrict__ out) {
  int wave = threadIdx.x >> 6, lane = threadIdx.x & 63;
  int r = blockIdx.x * 4 + wave;                    // one 64-lane wave per row
  float s = 0.f;
  #pragma unroll
  for (int k = 0; k < EG_N; ++k)
    s += (float)partials[(size_t)k * B_SZ * O_SZ + (size_t)r * O_SZ + lane];
  float m = s;
  #pragma unroll
  for (int off = 32; off; off >>= 1) m = fmaxf(m, __shfl_xor(m, off));
  float ex = expf(s - m), sum = ex;
  #pragma unroll
  for (int off = 32; off; off >>= 1) sum += __shfl_xor(sum, off);
  out[(size_t)r * O_SZ + lane] = s - m - logf(sum);
}

extern "C" void kernel_launch(void* const* d_in, const int* in_sizes, int n_in,
                              void* d_out, int out_size, void* d_ws, size_t ws_size,
                              hipStream_t stream) {
  const float* x    = (const float*)d_in[0];
  const float* ds   = (const float*)d_in[1];
  const float* ts   = (const float*)d_in[2];
  const float* W    = (const float*)d_in[3];
  const float* bias = (const float*)d_in[4];
  float* out = (float*)d_out;

  char* w = (char*)d_ws;
  __bf16* xb      = (__bf16*)(w);                   // 4 MB
  __bf16* wt      = (__bf16*)(w + (4ull  << 20));   // 8 MB
  float*  gT      = (float*) (w + (12ull << 20));   // 2 MB
  __bf16* parts   = (__bf16*)(w + (14ull << 20));   // 8 MB (16 slabs x 512KB)

  prep_xg   <<<2048, 256, 0, stream>>>(x, xb, ds, ts, gT);
  prep_w    <<<1024, 256, 0, stream>>>(W, wt);
  mtc_gemm  <<< 256, 512, 0, stream>>>(xb, wt, gT, bias, parts);
  mtc_reduce<<<1024, 256, 0, stream>>>(parts, out);
}